// Round 4
// baseline (204.487 us; speedup 1.0000x reference)
//
#include <hip/hip_runtime.h>
#include <math.h>
#include <stdint.h>

#define NUM_BINS 1000
#define MAX_MZ_F 1000.0f
#define B_ROWS 8192
#define N_COLS 2048
#define BLOCK 256

// log1p(exp(-1)) and ln(2) as f32-accurate constants
#define BCE_PE1 0.31326168751822286f
#define BCE_PE0 0.69314718055994531f

__device__ __forceinline__ float wave_reduce_add(float v) {
    #pragma unroll
    for (int off = 32; off > 0; off >>= 1)
        v += __shfl_xor(v, off, 64);
    return v;
}

// Bit-identical to reference: (int)(mz / 1000.0f * 999.0f)
__device__ __forceinline__ uint32_t bin_of(float mz) {
    return (uint32_t)(int)(mz / MAX_MZ_F * 999.0f);
}

// Native LDS fp add. Compiler refuses ds_add_f32 under IEEE-denorm f32 mode
// (HIP default) and emits a CAS retry loop instead -- inline asm bypasses it.
// Values are O(1): denormal flushing is irrelevant here.
__device__ __forceinline__ void lds_fadd_asm(uint32_t byte_addr, float v) {
    asm volatile("ds_add_f32 %0, %1" :: "v"(byte_addr), "v"(v) : "memory");
}

__global__ __launch_bounds__(BLOCK) void hybrid_loss_main(
    const float* __restrict__ pred_mz,
    const float* __restrict__ pred_in,
    const float* __restrict__ true_mz,
    const float* __restrict__ true_in,
    float4* __restrict__ part)   // part[row] = {cosl, bce, hub, cnt}
{
    // hist[0..999] = pred bins, hist[1024..2023] = true bins
    __shared__ float hist[2048];
    __shared__ float xred[4][6];

    const int row = blockIdx.x;
    const int tid = threadIdx.x;

    for (int i = tid; i < 2048; i += BLOCK) hist[i] = 0.0f;
    __syncthreads();

    // ---- binning ----
    {
        const float4* pmz = (const float4*)(pred_mz + (size_t)row * N_COLS);
        const float4* pin = (const float4*)(pred_in + (size_t)row * N_COLS);
        const float4* tmz = (const float4*)(true_mz + (size_t)row * N_COLS);
        const float4* tin = (const float4*)(true_in + (size_t)row * N_COLS);

        // 512 float4 per row, 256 threads: exactly 2 each. Hoist ALL loads
        // above the asm atomics (asm memory clobbers would block hoisting).
        float4 m0 = pmz[tid];       float4 v0 = pin[tid];
        float4 m1 = pmz[tid + 256]; float4 v1 = pin[tid + 256];
        float4 s0 = tmz[tid];       float4 w0 = tin[tid];
        float4 s1 = tmz[tid + 256]; float4 w1 = tin[tid + 256];

        const uint32_t hb = (uint32_t)(uintptr_t)&hist[0];
        const uint32_t tbase = hb + 4096u;   // hist + 1024 floats

        lds_fadd_asm(hb + 4u * bin_of(m0.x), v0.x);
        lds_fadd_asm(hb + 4u * bin_of(m0.y), v0.y);
        lds_fadd_asm(hb + 4u * bin_of(m0.z), v0.z);
        lds_fadd_asm(hb + 4u * bin_of(m0.w), v0.w);
        lds_fadd_asm(hb + 4u * bin_of(m1.x), v1.x);
        lds_fadd_asm(hb + 4u * bin_of(m1.y), v1.y);
        lds_fadd_asm(hb + 4u * bin_of(m1.z), v1.z);
        lds_fadd_asm(hb + 4u * bin_of(m1.w), v1.w);

        lds_fadd_asm(tbase + 4u * bin_of(s0.x), w0.x);
        lds_fadd_asm(tbase + 4u * bin_of(s0.y), w0.y);
        lds_fadd_asm(tbase + 4u * bin_of(s0.z), w0.z);
        lds_fadd_asm(tbase + 4u * bin_of(s0.w), w0.w);
        lds_fadd_asm(tbase + 4u * bin_of(s1.x), w1.x);
        lds_fadd_asm(tbase + 4u * bin_of(s1.y), w1.y);
        lds_fadd_asm(tbase + 4u * bin_of(s1.z), w1.z);
        lds_fadd_asm(tbase + 4u * bin_of(s1.w), w1.w);
    }
    // Compiler doesn't track asm DS ops -- drain before the barrier.
    asm volatile("s_waitcnt lgkmcnt(0)" ::: "memory");
    __syncthreads();

    // ---- per-bin loss terms ----
    float dot = 0.f, pn2 = 0.f, tn2 = 0.f, bce = 0.f, hub = 0.f, cnt = 0.f;
    for (int i = tid; i < NUM_BINS; i += BLOCK) {
        float p = hist[i];
        float t = hist[1024 + i];
        dot += p * t;
        pn2 += p * p;
        tn2 += t * t;
        float te = (t > 0.0f) ? 1.0f : 0.0f;
        bce += (p > 0.0f) ? (1.0f - te + BCE_PE1) : BCE_PE0;
        float d  = p - t;
        float ad = fabsf(d);
        float h  = (ad < 1.0f) ? (0.5f * d * d) : (ad - 0.5f);
        hub += h * te;
        cnt += te;
    }

    // ---- block reduction ----
    dot = wave_reduce_add(dot);
    pn2 = wave_reduce_add(pn2);
    tn2 = wave_reduce_add(tn2);
    bce = wave_reduce_add(bce);
    hub = wave_reduce_add(hub);
    cnt = wave_reduce_add(cnt);

    const int wave = tid >> 6;
    const int lane = tid & 63;
    if (lane == 0) {
        xred[wave][0] = dot; xred[wave][1] = pn2; xred[wave][2] = tn2;
        xred[wave][3] = bce; xred[wave][4] = hub; xred[wave][5] = cnt;
    }
    __syncthreads();

    if (tid == 0) {
        float a0 = 0.f, a1 = 0.f, a2 = 0.f, a3 = 0.f, a4 = 0.f, a5 = 0.f;
        #pragma unroll
        for (int w = 0; w < BLOCK / 64; ++w) {
            a0 += xred[w][0]; a1 += xred[w][1]; a2 += xred[w][2];
            a3 += xred[w][3]; a4 += xred[w][4]; a5 += xred[w][5];
        }
        float pn = fmaxf(sqrtf(a1), 1e-8f);
        float tn = fmaxf(sqrtf(a2), 1e-8f);
        float cosl = 1.0f - a0 / (pn * tn);
        float4 r;
        r.x = cosl; r.y = a3; r.z = a4; r.w = a5;
        part[row] = r;
    }
}

__global__ __launch_bounds__(256) void hybrid_loss_reduce(
    const float4* __restrict__ part,
    float* __restrict__ out)
{
    __shared__ double xr[4][4];
    const int tid = threadIdx.x;

    double c = 0.0, b = 0.0, h = 0.0, n = 0.0;
    for (int i = tid; i < B_ROWS; i += 256) {
        float4 v = part[i];
        c += (double)v.x; b += (double)v.y; h += (double)v.z; n += (double)v.w;
    }
    #pragma unroll
    for (int off = 32; off > 0; off >>= 1) {
        c += __shfl_xor(c, off, 64);
        b += __shfl_xor(b, off, 64);
        h += __shfl_xor(h, off, 64);
        n += __shfl_xor(n, off, 64);
    }
    const int wave = tid >> 6;
    const int lane = tid & 63;
    if (lane == 0) { xr[wave][0] = c; xr[wave][1] = b; xr[wave][2] = h; xr[wave][3] = n; }
    __syncthreads();

    if (tid == 0) {
        double C = 0.0, Bs = 0.0, H = 0.0, Nn = 0.0;
        #pragma unroll
        for (int w = 0; w < 4; ++w) {
            C += xr[w][0]; Bs += xr[w][1]; H += xr[w][2]; Nn += xr[w][3];
        }
        double loss_cos  = C / (double)B_ROWS;
        double loss_peak = Bs / ((double)B_ROWS * (double)NUM_BINS);
        double cnt       = Nn < 1.0 ? 1.0 : Nn;
        double loss_int  = H / cnt;
        out[0] = (float)(0.4 * loss_cos + 0.3 * loss_peak + 0.2 * loss_int);
    }
}

extern "C" void kernel_launch(void* const* d_in, const int* in_sizes, int n_in,
                              void* d_out, int out_size, void* d_ws, size_t ws_size,
                              hipStream_t stream) {
    const float* pred_mz = (const float*)d_in[0];
    const float* pred_in = (const float*)d_in[1];
    const float* true_mz = (const float*)d_in[2];
    const float* true_in = (const float*)d_in[3];
    float4* part = (float4*)d_ws;   // 8192 * 16 B = 128 KiB
    float* out = (float*)d_out;

    hybrid_loss_main<<<B_ROWS, BLOCK, 0, stream>>>(pred_mz, pred_in, true_mz, true_in, part);
    hybrid_loss_reduce<<<1, 256, 0, stream>>>(part, out);
}

// Round 5
// 189.329 us; speedup vs baseline: 1.0801x; 1.0801x over previous
//
#include <hip/hip_runtime.h>
#include <math.h>
#include <stdint.h>

#define NUM_BINS 1000
#define MAX_MZ_F 1000.0f
#define B_ROWS 8192
#define N_COLS 2048
#define BLOCK 256
#define NBLOCKS 1024
#define NWAVES (NBLOCKS * 4)      // 4096 waves
#define ROWS_PER_WAVE (B_ROWS / NWAVES)  // 2

// log1p(exp(-1)) and ln(2) as f32-accurate constants
#define BCE_PE1 0.31326168751822286f
#define BCE_PE0 0.69314718055994531f

// Bit-identical to reference: (int)(mz / 1000.0f * 999.0f)
__device__ __forceinline__ uint32_t bin_of(float mz) {
    return (uint32_t)(int)(mz / MAX_MZ_F * 999.0f);
}

// Native LDS fp add, NO memory clobber: lets the compiler hoist the next
// chunk's global loads above these. Ordering vs LDS zero/read phases is
// enforced by explicit compile barriers + lgkmcnt waits below.
__device__ __forceinline__ void lds_fadd_asm(uint32_t byte_addr, float v) {
    asm volatile("ds_add_f32 %0, %1" :: "v"(byte_addr), "v"(v));
}

__device__ __forceinline__ float wave_reduce_add(float v) {
    #pragma unroll
    for (int off = 32; off > 0; off >>= 1)
        v += __shfl_xor(v, off, 64);
    return v;
}

__global__ __launch_bounds__(BLOCK, 4) void hybrid_loss_main(
    const float* __restrict__ pred_mz,
    const float* __restrict__ pred_in,
    const float* __restrict__ true_mz,
    const float* __restrict__ true_in,
    float4* __restrict__ part)   // part[row] = {cosl, bce, hub, cnt}
{
    // Per-WAVE private histograms: [0..1023]=pred, [1024..2047]=true.
    // No __syncthreads anywhere: waves are fully independent.
    __shared__ float hist[4][2048];

    const int tid  = threadIdx.x;
    const int wv   = tid >> 6;
    const int lane = tid & 63;
    const int w    = blockIdx.x * 4 + wv;

    float* h = hist[wv];
    const uint32_t hb = (uint32_t)(uintptr_t)h;   // pred hist base (bytes)
    const uint32_t tbase = hb + 4096u;            // true hist base

    for (int r = 0; r < ROWS_PER_WAVE; ++r) {
        const int row = r * NWAVES + w;   // concurrent waves sweep contiguous rows

        // ---- zero both hists: 512 float4, 8 per lane, stride-64 (conflict-free) ----
        {
            float4 z = make_float4(0.f, 0.f, 0.f, 0.f);
            float4* h4 = (float4*)h;
            #pragma unroll
            for (int j = 0; j < 8; ++j) h4[lane + 64 * j] = z;
        }
        asm volatile("" ::: "memory");   // zeros complete-in-order before atomics (DS in-order per wave)

        // ---- binning: 8 float4 per lane per array, coalesced stride-64 ----
        {
            const float4* pmz = (const float4*)(pred_mz + (size_t)row * N_COLS);
            const float4* pin = (const float4*)(pred_in + (size_t)row * N_COLS);
            const float4* tmz = (const float4*)(true_mz + (size_t)row * N_COLS);
            const float4* tin = (const float4*)(true_in + (size_t)row * N_COLS);
            #pragma unroll 4
            for (int k = 0; k < 8; ++k) {
                const int idx = lane + 64 * k;
                float4 m = pmz[idx];
                float4 v = pin[idx];
                float4 s = tmz[idx];
                float4 u = tin[idx];
                lds_fadd_asm(hb + 4u * bin_of(m.x), v.x);
                lds_fadd_asm(hb + 4u * bin_of(m.y), v.y);
                lds_fadd_asm(hb + 4u * bin_of(m.z), v.z);
                lds_fadd_asm(hb + 4u * bin_of(m.w), v.w);
                lds_fadd_asm(tbase + 4u * bin_of(s.x), u.x);
                lds_fadd_asm(tbase + 4u * bin_of(s.y), u.y);
                lds_fadd_asm(tbase + 4u * bin_of(s.z), u.z);
                lds_fadd_asm(tbase + 4u * bin_of(s.w), u.w);
            }
        }
        // Drain untracked asm DS ops; memory clobber also kills store-to-load
        // forwarding of the zeros into the loss pass.
        asm volatile("s_waitcnt lgkmcnt(0)" ::: "memory");

        // ---- per-bin loss terms: lane handles bins {lane, lane+64, ...} (conflict-free) ----
        float dot = 0.f, pn2 = 0.f, tn2 = 0.f, bce = 0.f, hub = 0.f, cnt = 0.f;
        #pragma unroll
        for (int k = 0; k < 16; ++k) {
            const int i = lane + 64 * k;
            float p = h[i];
            float t = h[1024 + i];
            float valid = (i < NUM_BINS) ? 1.0f : 0.0f;  // only k==15 partial
            dot += p * t;
            pn2 += p * p;
            tn2 += t * t;
            float te = (t > 0.0f) ? 1.0f : 0.0f;
            float bt = (p > 0.0f) ? (1.0f - te + BCE_PE1) : BCE_PE0;
            bce += valid * bt;
            float d  = p - t;
            float ad = fabsf(d);
            float hh = (ad < 1.0f) ? (0.5f * d * d) : (ad - 0.5f);
            hub += hh * te;
            cnt += te;
        }

        // ---- wave reduction, lane 0 writes the row partial ----
        dot = wave_reduce_add(dot);
        pn2 = wave_reduce_add(pn2);
        tn2 = wave_reduce_add(tn2);
        bce = wave_reduce_add(bce);
        hub = wave_reduce_add(hub);
        cnt = wave_reduce_add(cnt);

        if (lane == 0) {
            float pn = fmaxf(sqrtf(pn2), 1e-8f);
            float tn = fmaxf(sqrtf(tn2), 1e-8f);
            float4 rr;
            rr.x = 1.0f - dot / (pn * tn);
            rr.y = bce; rr.z = hub; rr.w = cnt;
            part[row] = rr;
        }
        asm volatile("" ::: "memory");   // loss reads stay before next row's zeroing
    }
}

__global__ __launch_bounds__(256) void hybrid_loss_reduce(
    const float4* __restrict__ part,
    float* __restrict__ out)
{
    __shared__ double xr[4][4];
    const int tid = threadIdx.x;

    double c = 0.0, b = 0.0, h = 0.0, n = 0.0;
    for (int i = tid; i < B_ROWS; i += 256) {
        float4 v = part[i];
        c += (double)v.x; b += (double)v.y; h += (double)v.z; n += (double)v.w;
    }
    #pragma unroll
    for (int off = 32; off > 0; off >>= 1) {
        c += __shfl_xor(c, off, 64);
        b += __shfl_xor(b, off, 64);
        h += __shfl_xor(h, off, 64);
        n += __shfl_xor(n, off, 64);
    }
    const int wave = tid >> 6;
    const int lane = tid & 63;
    if (lane == 0) { xr[wave][0] = c; xr[wave][1] = b; xr[wave][2] = h; xr[wave][3] = n; }
    __syncthreads();

    if (tid == 0) {
        double C = 0.0, Bs = 0.0, H = 0.0, Nn = 0.0;
        #pragma unroll
        for (int w = 0; w < 4; ++w) {
            C += xr[w][0]; Bs += xr[w][1]; H += xr[w][2]; Nn += xr[w][3];
        }
        double loss_cos  = C / (double)B_ROWS;
        double loss_peak = Bs / ((double)B_ROWS * (double)NUM_BINS);
        double cnt       = Nn < 1.0 ? 1.0 : Nn;
        double loss_int  = H / cnt;
        out[0] = (float)(0.4 * loss_cos + 0.3 * loss_peak + 0.2 * loss_int);
    }
}

extern "C" void kernel_launch(void* const* d_in, const int* in_sizes, int n_in,
                              void* d_out, int out_size, void* d_ws, size_t ws_size,
                              hipStream_t stream) {
    const float* pred_mz = (const float*)d_in[0];
    const float* pred_in = (const float*)d_in[1];
    const float* true_mz = (const float*)d_in[2];
    const float* true_in = (const float*)d_in[3];
    float4* part = (float4*)d_ws;   // 8192 * 16 B = 128 KiB
    float* out = (float*)d_out;

    hybrid_loss_main<<<NBLOCKS, BLOCK, 0, stream>>>(pred_mz, pred_in, true_mz, true_in, part);
    hybrid_loss_reduce<<<1, 256, 0, stream>>>(part, out);
}

// Round 6
// 55.161 us; speedup vs baseline: 3.7071x; 3.4323x over previous
//
#include <hip/hip_runtime.h>
#include <math.h>
#include <stdint.h>

#define NUM_BINS 1000
#define MAX_MZ_F 1000.0f
#define B_ROWS 8192
#define N_COLS 2048
#define BLOCK 256
#define NBLOCKS 1024
#define NWAVES (NBLOCKS * 4)      // 4096 waves
#define ROWS_PER_WAVE (B_ROWS / NWAVES)  // 2

// Fixed-point scale for intensity accumulation (integer LDS atomics).
// Bin sums < 2048, so 2^20 scale stays < 2^31. Quantization error ~5e-7/elem.
#define QSCALE_F 1048576.0f
#define QINV_F   (1.0f / 1048576.0f)

// log1p(exp(-1)) and ln(2) as f32-accurate constants
#define BCE_PE1 0.31326168751822286f
#define BCE_PE0 0.69314718055994531f

// Bit-identical to reference: (int)(mz / 1000.0f * 999.0f)
__device__ __forceinline__ int bin_of(float mz) {
    return (int)(mz / MAX_MZ_F * 999.0f);
}

__device__ __forceinline__ float wave_reduce_add(float v) {
    #pragma unroll
    for (int off = 32; off > 0; off >>= 1)
        v += __shfl_xor(v, off, 64);
    return v;
}

__global__ __launch_bounds__(BLOCK, 4) void hybrid_loss_main(
    const float* __restrict__ pred_mz,
    const float* __restrict__ pred_in,
    const float* __restrict__ true_mz,
    const float* __restrict__ true_in,
    float4* __restrict__ part)   // part[row] = {cosl, bce, hub, cnt}
{
    // Per-WAVE private integer histograms: [0..1023]=pred, [1024..2047]=true.
    // Wave-private + wave-lockstep DS ordering => no __syncthreads needed.
    __shared__ unsigned int hist[4][2048];

    const int tid  = threadIdx.x;
    const int wv   = tid >> 6;
    const int lane = tid & 63;
    const int w    = blockIdx.x * 4 + wv;

    unsigned int* h = hist[wv];

    for (int r = 0; r < ROWS_PER_WAVE; ++r) {
        const int row = r * NWAVES + w;   // concurrent waves sweep contiguous rows

        // ---- zero both hists: 512 uint4, 8 per lane, stride-64 (conflict-free) ----
        {
            uint4 z = make_uint4(0u, 0u, 0u, 0u);
            uint4* h4 = (uint4*)h;
            #pragma unroll
            for (int j = 0; j < 8; ++j) h4[lane + 64 * j] = z;
        }

        // ---- binning: quantize to fixed-point, integer LDS atomics ----
        {
            const float4* pmz = (const float4*)(pred_mz + (size_t)row * N_COLS);
            const float4* pin = (const float4*)(pred_in + (size_t)row * N_COLS);
            const float4* tmz = (const float4*)(true_mz + (size_t)row * N_COLS);
            const float4* tin = (const float4*)(true_in + (size_t)row * N_COLS);
            #pragma unroll 4
            for (int k = 0; k < 8; ++k) {
                const int idx = lane + 64 * k;
                float4 m = pmz[idx];
                float4 v = pin[idx];
                float4 s = tmz[idx];
                float4 u = tin[idx];
                atomicAdd(&h[bin_of(m.x)], __float2uint_rn(v.x * QSCALE_F));
                atomicAdd(&h[bin_of(m.y)], __float2uint_rn(v.y * QSCALE_F));
                atomicAdd(&h[bin_of(m.z)], __float2uint_rn(v.z * QSCALE_F));
                atomicAdd(&h[bin_of(m.w)], __float2uint_rn(v.w * QSCALE_F));
                atomicAdd(&h[1024 + bin_of(s.x)], __float2uint_rn(u.x * QSCALE_F));
                atomicAdd(&h[1024 + bin_of(s.y)], __float2uint_rn(u.y * QSCALE_F));
                atomicAdd(&h[1024 + bin_of(s.z)], __float2uint_rn(u.z * QSCALE_F));
                atomicAdd(&h[1024 + bin_of(s.w)], __float2uint_rn(u.w * QSCALE_F));
            }
        }

        // ---- per-bin loss terms: lane handles bins {lane, lane+64, ...} ----
        // Same-wave DS ops are in-order; hist is wave-private => reads see all adds.
        float dot = 0.f, pn2 = 0.f, tn2 = 0.f, bce = 0.f, hub = 0.f, cnt = 0.f;
        #pragma unroll
        for (int k = 0; k < 16; ++k) {
            const int i = lane + 64 * k;
            unsigned int pq = h[i];
            unsigned int tq = h[1024 + i];
            float p = (float)pq * QINV_F;
            float t = (float)tq * QINV_F;
            float valid = (i < NUM_BINS) ? 1.0f : 0.0f;  // only k==15 partial
            dot += p * t;
            pn2 += p * p;
            tn2 += t * t;
            float te = (tq != 0u) ? 1.0f : 0.0f;
            float bt = (pq != 0u) ? (1.0f - te + BCE_PE1) : BCE_PE0;
            bce += valid * bt;
            float d  = p - t;
            float ad = fabsf(d);
            float hh = (ad < 1.0f) ? (0.5f * d * d) : (ad - 0.5f);
            hub += hh * te;
            cnt += te;
        }

        // ---- wave reduction, lane 0 writes the row partial ----
        dot = wave_reduce_add(dot);
        pn2 = wave_reduce_add(pn2);
        tn2 = wave_reduce_add(tn2);
        bce = wave_reduce_add(bce);
        hub = wave_reduce_add(hub);
        cnt = wave_reduce_add(cnt);

        if (lane == 0) {
            float pn = fmaxf(sqrtf(pn2), 1e-8f);
            float tn = fmaxf(sqrtf(tn2), 1e-8f);
            float4 rr;
            rr.x = 1.0f - dot / (pn * tn);
            rr.y = bce; rr.z = hub; rr.w = cnt;
            part[row] = rr;
        }
    }
}

__global__ __launch_bounds__(256) void hybrid_loss_reduce(
    const float4* __restrict__ part,
    float* __restrict__ out)
{
    __shared__ double xr[4][4];
    const int tid = threadIdx.x;

    double c = 0.0, b = 0.0, h = 0.0, n = 0.0;
    for (int i = tid; i < B_ROWS; i += 256) {
        float4 v = part[i];
        c += (double)v.x; b += (double)v.y; h += (double)v.z; n += (double)v.w;
    }
    #pragma unroll
    for (int off = 32; off > 0; off >>= 1) {
        c += __shfl_xor(c, off, 64);
        b += __shfl_xor(b, off, 64);
        h += __shfl_xor(h, off, 64);
        n += __shfl_xor(n, off, 64);
    }
    const int wave = tid >> 6;
    const int lane = tid & 63;
    if (lane == 0) { xr[wave][0] = c; xr[wave][1] = b; xr[wave][2] = h; xr[wave][3] = n; }
    __syncthreads();

    if (tid == 0) {
        double C = 0.0, Bs = 0.0, H = 0.0, Nn = 0.0;
        #pragma unroll
        for (int w = 0; w < 4; ++w) {
            C += xr[w][0]; Bs += xr[w][1]; H += xr[w][2]; Nn += xr[w][3];
        }
        double loss_cos  = C / (double)B_ROWS;
        double loss_peak = Bs / ((double)B_ROWS * (double)NUM_BINS);
        double cnt       = Nn < 1.0 ? 1.0 : Nn;
        double loss_int  = H / cnt;
        out[0] = (float)(0.4 * loss_cos + 0.3 * loss_peak + 0.2 * loss_int);
    }
}

extern "C" void kernel_launch(void* const* d_in, const int* in_sizes, int n_in,
                              void* d_out, int out_size, void* d_ws, size_t ws_size,
                              hipStream_t stream) {
    const float* pred_mz = (const float*)d_in[0];
    const float* pred_in = (const float*)d_in[1];
    const float* true_mz = (const float*)d_in[2];
    const float* true_in = (const float*)d_in[3];
    float4* part = (float4*)d_ws;   // 8192 * 16 B = 128 KiB
    float* out = (float*)d_out;

    hybrid_loss_main<<<NBLOCKS, BLOCK, 0, stream>>>(pred_mz, pred_in, true_mz, true_in, part);
    hybrid_loss_reduce<<<1, 256, 0, stream>>>(part, out);
}